// Round 8
// baseline (106.384 us; speedup 1.0000x reference)
//
#include <hip/hip_runtime.h>
#include <hip/hip_bf16.h>

// RBF collocation, N=6144, 17 outputs (closed-form nested JVPs of Gaussian RBF).
// MFMA factorization (validated R5-R7): out = linear-epilogue( W = G @ V ),
//   G[i,j] = exp(-0.5*||c_j - p_i||^2)  (bf16 A-fragments computed in-lane),
//   V [N x 21] = {v1,cx*v1,cz*v1 | v_k,cx*v_k,cz*v_k,ct*v_k,cx^2*v_k,cz^2*v_k}.
// R8: remove 417k cross-XCD atomicAdds (direct f32x4 W-tile stores + finish
// kernel); remove prep (per-block in-LDS staging of c-slice and V-slice);
// pre-scale coords by sqrt(log2e/2) so exp2 needs no extra mul.
// Dtypes proven R1-R3: inputs fp32, output fp32.

#define NPTS 6144
#define SPLIT 16
#define KC (NPTS / SPLIT)     // 384 j per block
#define NSTEP (KC / 32)       // 12 MFMA K-steps
#define VROW 392              // LDS V row stride (bf16): 784B, 16B-aligned
#define SCALE 0.8493218002880191f   // sqrt(0.72134752) ; S^2 = log2(e)/2

typedef float  f32x4  __attribute__((ext_vector_type(4)));
typedef __bf16 bf16x8 __attribute__((ext_vector_type(8)));

#if defined(__has_builtin) && __has_builtin(__builtin_amdgcn_exp2f)
#define EXP2F(x) __builtin_amdgcn_exp2f(x)
#else
#define EXP2F(x) __expf((x) * 0.6931471805599453f)
#endif

// V-column order: 0:v1 1:cx*v1 2:cz*v1 | 3..8: v2 {1,cx,cz,ct,cx2,cz2}
// | 9..14: v3 same | 15..20: v4 same.
// part layout: [s][col 21][row NPTS]  (col-major rows for coalesced finish)
__global__ __launch_bounds__(256, 6) void rbf_main4(
    const float* __restrict__ xp, const float* __restrict__ zp,
    const float* __restrict__ tp, const float* __restrict__ cp,
    const float* __restrict__ v1p, const float* __restrict__ v2p,
    const float* __restrict__ v3p, const float* __restrict__ v4p,
    float* __restrict__ part) {
  __shared__ __align__(16) float  cs[3][KC];       // scaled c slice, 4608 B
  __shared__ __align__(16) __bf16 vlds[21][VROW];  // V slice, 16464 B

  const int s  = blockIdx.x / 96;       // K-split 0..15
  const int rg = blockIdx.x % 96;       // row-group (64 rows)

  // ---- in-block staging: c-slice (fp32, scaled) + V-slice (bf16) ----
  for (int j = threadIdx.x; j < KC; j += 256) {
    const int jg = s * KC + j;
    const float cx = cp[3 * jg], cz = cp[3 * jg + 1], ct = cp[3 * jg + 2];
    cs[0][j] = cx * SCALE; cs[1][j] = cz * SCALE; cs[2][j] = ct * SCALE;
    const float a1 = v1p[jg];
    vlds[0][j] = (__bf16)a1;
    vlds[1][j] = (__bf16)(cx * a1);
    vlds[2][j] = (__bf16)(cz * a1);
    const float vs[3] = {v2p[jg], v3p[jg], v4p[jg]};
#pragma unroll
    for (int k2 = 0; k2 < 3; ++k2) {
      const float v = vs[k2];
      const int r = 3 + 6 * k2;
      vlds[r + 0][j] = (__bf16)v;
      vlds[r + 1][j] = (__bf16)(cx * v);
      vlds[r + 2][j] = (__bf16)(cz * v);
      vlds[r + 3][j] = (__bf16)(ct * v);
      vlds[r + 4][j] = (__bf16)(cx * cx * v);
      vlds[r + 5][j] = (__bf16)(cz * cz * v);
    }
  }
  __syncthreads();

  const int w    = threadIdx.x >> 6;
  const int lane = threadIdx.x & 63;
  const int lo   = lane & 15;           // A row / D col / B col
  const int hi   = lane >> 4;           // k-group: lane holds k = hi*8 + i
  const int lo5  = lo % 5;              // acc1 B row (garbage cols discarded)

  const int rowbase = rg * 64 + w * 16; // wave owns 16 rows
  const int row = rowbase + lo;
  const float xs = xp[row] * SCALE, zs = zp[row] * SCALE, ts = tp[row] * SCALE;

  const __bf16* __restrict__ vb0 = &vlds[lo][0];        // cols 0..15
  const __bf16* __restrict__ vb1 = &vlds[16 + lo5][0];  // cols 16..20 (lo<5 real)

  f32x4 acc0 = {0.f, 0.f, 0.f, 0.f};
  f32x4 acc1 = {0.f, 0.f, 0.f, 0.f};

#pragma unroll 2
  for (int step = 0; step < NSTEP; ++step) {
    const int kb = hi * 8 + step * 32;
    const f32x4 cx0 = *(const f32x4*)&cs[0][kb];
    const f32x4 cx1 = *(const f32x4*)&cs[0][kb + 4];
    const f32x4 cz0 = *(const f32x4*)&cs[1][kb];
    const f32x4 cz1 = *(const f32x4*)&cs[1][kb + 4];
    const f32x4 ct0 = *(const f32x4*)&cs[2][kb];
    const f32x4 ct1 = *(const f32x4*)&cs[2][kb + 4];
    const bf16x8 b0 = *(const bf16x8*)(vb0 + kb);
    const bf16x8 b1 = *(const bf16x8*)(vb1 + kb);

    bf16x8 af;
#pragma unroll
    for (int i = 0; i < 4; ++i) {
      const float dx = cx0[i] - xs, dz = cz0[i] - zs, dt = ct0[i] - ts;
      const float r2 = fmaf(dx, dx, fmaf(dz, dz, dt * dt));  // = 0.7213*r2_true
      af[i] = (__bf16)EXP2F(-r2);                            // exp(-0.5*r2_true)
    }
#pragma unroll
    for (int i = 0; i < 4; ++i) {
      const float dx = cx1[i] - xs, dz = cz1[i] - zs, dt = ct1[i] - ts;
      const float r2 = fmaf(dx, dx, fmaf(dz, dz, dt * dt));
      af[4 + i] = (__bf16)EXP2F(-r2);
    }
    acc0 = __builtin_amdgcn_mfma_f32_16x16x32_bf16(af, b0, acc0, 0, 0, 0);
    acc1 = __builtin_amdgcn_mfma_f32_16x16x32_bf16(af, b1, acc1, 0, 0, 0);
  }

  // ---- direct W-tile store. D layout: col=lane&15, row=hi*4+reg -> the 4
  // regs are 4 consecutive rows => one f32x4 store per lane. ----
  float* p0 = part + ((size_t)(s * 21 + lo)) * NPTS + rowbase + hi * 4;
  *(f32x4*)p0 = acc0;
  if (lo < 5) {
    float* p1 = part + ((size_t)(s * 21 + 16 + lo)) * NPTS + rowbase + hi * 4;
    *(f32x4*)p1 = acc1;
  }
}

__global__ __launch_bounds__(256) void rbf_finish4(
    const float* __restrict__ part,
    const float* __restrict__ xp, const float* __restrict__ zp,
    const float* __restrict__ tp,
    float* __restrict__ out) {
  const int tid = blockIdx.x * 256 + threadIdx.x;
  const int row = tid >> 2;
  const int q   = tid & 3;              // each q sums 4 of the 16 splits

  float wv[21];
#pragma unroll
  for (int c = 0; c < 21; ++c) wv[c] = 0.f;
#pragma unroll
  for (int s4 = 0; s4 < 4; ++s4) {
    const int s = q * 4 + s4;
    const float* p = part + (size_t)s * 21 * NPTS + row;
#pragma unroll
    for (int c = 0; c < 21; ++c) wv[c] += p[(size_t)c * NPTS];
  }
#pragma unroll
  for (int c = 0; c < 21; ++c) {
    wv[c] += __shfl_xor(wv[c], 1, 4);
    wv[c] += __shfl_xor(wv[c], 2, 4);
  }
  if (q == 0) {
    const float x = xp[row], z = zp[row], t = tp[row];
    const float x2 = fmaf(x, x, -1.f), z2 = fmaf(z, z, -1.f);
    float* o = out;
    o[0 * NPTS + row]  = wv[10] - x * wv[9];                        // dudx
    o[1 * NPTS + row]  = wv[11] - z * wv[9];                        // dudz
    o[2 * NPTS + row]  = wv[12] - t * wv[9];                        // dudt
    o[3 * NPTS + row]  = wv[16] - x * wv[15];                       // dwdx
    o[4 * NPTS + row]  = wv[17] - z * wv[15];                       // dwdz
    o[5 * NPTS + row]  = wv[18] - t * wv[15];                       // dwdt
    o[6 * NPTS + row]  = wv[4]  - x * wv[3];                        // dbdx
    o[7 * NPTS + row]  = wv[5]  - z * wv[3];                        // dbdz
    o[8 * NPTS + row]  = wv[6]  - t * wv[3];                        // dbdt
    o[9 * NPTS + row]  = wv[1]  - x * wv[0];                        // dpdx
    o[10 * NPTS + row] = wv[2]  - z * wv[0];                        // dpdz
    o[11 * NPTS + row] = wv[13] - 2.f * x * wv[10] + x2 * wv[9];    // d2u2x
    o[12 * NPTS + row] = wv[14] - 2.f * z * wv[11] + z2 * wv[9];    // d2u2z
    o[13 * NPTS + row] = wv[19] - 2.f * x * wv[16] + x2 * wv[15];   // d2w2x
    o[14 * NPTS + row] = wv[20] - 2.f * z * wv[17] + z2 * wv[15];   // d2w2z
    o[15 * NPTS + row] = wv[7]  - 2.f * x * wv[4]  + x2 * wv[3];    // d2b2x
    o[16 * NPTS + row] = wv[8]  - 2.f * z * wv[5]  + z2 * wv[3];    // d2b2z
  }
}

extern "C" void kernel_launch(void* const* d_in, const int* in_sizes, int n_in,
                              void* d_out, int out_size, void* d_ws, size_t ws_size,
                              hipStream_t stream) {
  const float* xp  = (const float*)d_in[0];
  const float* zp  = (const float*)d_in[1];
  const float* tp  = (const float*)d_in[2];
  const float* cp  = (const float*)d_in[3];
  const float* v1p = (const float*)d_in[4];
  const float* v2p = (const float*)d_in[5];
  const float* v3p = (const float*)d_in[6];
  const float* v4p = (const float*)d_in[7];

  float* part = (float*)d_ws;   // 16*21*6144 floats = 8.26 MB

  rbf_main4<<<96 * SPLIT, 256, 0, stream>>>(xp, zp, tp, cp, v1p, v2p, v3p, v4p,
                                            part);

  rbf_finish4<<<(NPTS * 4) / 256, 256, 0, stream>>>(part, xp, zp, tp,
                                                    (float*)d_out);
}

// Round 9
// 91.062 us; speedup vs baseline: 1.1683x; 1.1683x over previous
//
#include <hip/hip_runtime.h>
#include <hip/hip_bf16.h>

// RBF collocation, N=6144, 17 outputs (closed-form nested JVPs of Gaussian RBF).
// MFMA factorization (validated R5-R8): out = linear-epilogue( W = G @ V ),
//   G[i,j] = exp(-0.5*||c_j - p_i||^2)  (bf16 A-fragments computed in-lane),
//   V [N x 21] = {v1,cx*v1,cz*v1 | v_k,cx*v_k,cz*v_k,ct*v_k,cx^2*v_k,cz^2*v_k}.
// R9 = revert to R7 structure (best measured 90.5 us; R8's part+finish rewrite
// regressed to 106.4, suspected launch_bounds-min-wave spill) with micro-opts:
// pre-scaled coords (exp2 needs no mul), Vt 32->21 rows (vb1 = row 16+lo%5),
// smem 25.1->16.5 KB. Dtypes proven R1-R3: inputs fp32, output fp32.

#define NPTS 6144
#define NOUTS (17 * NPTS)
#define SPLIT 16
#define KC (NPTS / SPLIT)     // 384 j per block
#define NSTEP (KC / 32)       // 12 MFMA K-steps
#define VROW 392              // LDS V row stride (bf16): 784 B, 16B-aligned
#define SCALE 0.8493218002880191f   // sqrt(log2(e)/2); dx'^2 = 0.72134*dx^2

typedef float  f32x4  __attribute__((ext_vector_type(4)));
typedef __bf16 bf16x8 __attribute__((ext_vector_type(8)));

#if defined(__has_builtin) && __has_builtin(__builtin_amdgcn_exp2f)
#define EXP2F(x) __builtin_amdgcn_exp2f(x)
#else
#define EXP2F(x) __expf((x) * 0.6931471805599453f)
#endif

// V-column order: 0:v1 1:cx*v1 2:cz*v1 | 3..8: v2 {1,cx,cz,ct,cx2,cz2}
// | 9..14: v3 same | 15..20: v4 same
__global__ void rbf_prep(const float* __restrict__ cp,
                         const float* __restrict__ v1p,
                         const float* __restrict__ v2p,
                         const float* __restrict__ v3p,
                         const float* __restrict__ v4p,
                         float* __restrict__ cxa, float* __restrict__ cza,
                         float* __restrict__ cta, __bf16* __restrict__ vt,
                         float* __restrict__ out) {
  const int j = blockIdx.x * blockDim.x + threadIdx.x;
  // zero d_out (poisoned 0xAA each call; main accumulates atomically)
  for (int i = j; i < NOUTS; i += NPTS) out[i] = 0.f;
  const float cx = cp[3 * j], cz = cp[3 * j + 1], ct = cp[3 * j + 2];
  cxa[j] = cx * SCALE; cza[j] = cz * SCALE; cta[j] = ct * SCALE;
  const float a1 = v1p[j];
  vt[0 * NPTS + j] = (__bf16)a1;
  vt[1 * NPTS + j] = (__bf16)(cx * a1);
  vt[2 * NPTS + j] = (__bf16)(cz * a1);
#pragma unroll
  for (int k = 0; k < 3; ++k) {         // v2, v3, v4
    const float v = (k == 0) ? v2p[j] : (k == 1) ? v3p[j] : v4p[j];
    const int r = 3 + 6 * k;
    vt[(r + 0) * NPTS + j] = (__bf16)v;
    vt[(r + 1) * NPTS + j] = (__bf16)(cx * v);
    vt[(r + 2) * NPTS + j] = (__bf16)(cz * v);
    vt[(r + 3) * NPTS + j] = (__bf16)(ct * v);
    vt[(r + 4) * NPTS + j] = (__bf16)(cx * cx * v);
    vt[(r + 5) * NPTS + j] = (__bf16)(cz * cz * v);
  }
}

__global__ __launch_bounds__(256) void rbf_main3(
    const float* __restrict__ xp, const float* __restrict__ zp,
    const float* __restrict__ tp,
    const float* __restrict__ cxa, const float* __restrict__ cza,
    const float* __restrict__ cta,
    const __bf16* __restrict__ vt,
    float* __restrict__ out) {
  __shared__ __align__(16) unsigned char smem[21 * VROW * 2];  // 16464 B
  __bf16 (*vlds)[VROW] = reinterpret_cast<__bf16(*)[VROW]>(smem);

  const int rg = blockIdx.x % 96;       // row-group (64 rows)
  const int s  = blockIdx.x / 96;       // K-split 0..15
  const int w    = threadIdx.x >> 6;
  const int lane = threadIdx.x & 63;
  const int lo   = lane & 15;           // A row / D col / B col
  const int hi   = lane >> 4;           // k-group: lane holds k = hi*8 + i
  const int lo5  = lo % 5;              // vb1 row (acc1 cols >=5 discarded)

  // ---- stage Vt[21][KC] slice into LDS, coalesced 16B chunks ----
  {
    const __bf16* src = vt + s * KC;
#pragma unroll
    for (int it = 0; it < 4; ++it) {    // 21 rows * 48 chunks = 1008 / 256
      const int idx = threadIdx.x + it * 256;
      if (idx < 21 * 48) {
        const int c = idx / 48, ch = idx % 48;
        *(bf16x8*)&vlds[c][ch * 8] =
            *(const bf16x8*)(src + (size_t)c * NPTS + ch * 8);
      }
    }
  }
  __syncthreads();

  const int rowbase = rg * 64 + w * 16;
  const int row = rowbase + lo;
  const float xs = xp[row] * SCALE, zs = zp[row] * SCALE, ts = tp[row] * SCALE;

  const float* __restrict__ cxg = cxa + s * KC;
  const float* __restrict__ czg = cza + s * KC;
  const float* __restrict__ ctg = cta + s * KC;

  f32x4 acc0 = {0.f, 0.f, 0.f, 0.f};
  f32x4 acc1 = {0.f, 0.f, 0.f, 0.f};

#pragma unroll 2
  for (int step = 0; step < NSTEP; ++step) {
    const int kb = hi * 8 + step * 32;
    const f32x4 cx0 = *(const f32x4*)(cxg + kb);
    const f32x4 cx1 = *(const f32x4*)(cxg + kb + 4);
    const f32x4 cz0 = *(const f32x4*)(czg + kb);
    const f32x4 cz1 = *(const f32x4*)(czg + kb + 4);
    const f32x4 ct0 = *(const f32x4*)(ctg + kb);
    const f32x4 ct1 = *(const f32x4*)(ctg + kb + 4);
    const bf16x8 b0 = *(const bf16x8*)&vlds[lo][kb];         // cols 0..15
    const bf16x8 b1 = *(const bf16x8*)&vlds[16 + lo5][kb];   // cols 16..20

    bf16x8 af;
#pragma unroll
    for (int i = 0; i < 4; ++i) {
      const float dx = cx0[i] - xs, dz = cz0[i] - zs, dt = ct0[i] - ts;
      const float r2 = fmaf(dx, dx, fmaf(dz, dz, dt * dt));  // pre-scaled
      af[i] = (__bf16)EXP2F(-r2);                            // = exp(-0.5*r2)
    }
#pragma unroll
    for (int i = 0; i < 4; ++i) {
      const float dx = cx1[i] - xs, dz = cz1[i] - zs, dt = ct1[i] - ts;
      const float r2 = fmaf(dx, dx, fmaf(dz, dz, dt * dt));
      af[4 + i] = (__bf16)EXP2F(-r2);
    }
    acc0 = __builtin_amdgcn_mfma_f32_16x16x32_bf16(af, b0, acc0, 0, 0, 0);
    acc1 = __builtin_amdgcn_mfma_f32_16x16x32_bf16(af, b1, acc1, 0, 0, 0);
  }

  // ---- W tile -> LDS (reuse staging area), then per-row atomic epilogue ----
  __syncthreads();                       // all waves done reading vlds
  float* redw = reinterpret_cast<float*>(smem) + w * (16 * 33);
  // D layout: col = lane&15, row = (lane>>4)*4 + reg  [m89-verified]
#pragma unroll
  for (int reg = 0; reg < 4; ++reg) {
    const int r = hi * 4 + reg;
    redw[r * 33 + lo]      = acc0[reg];
    redw[r * 33 + lo + 16] = acc1[reg];
  }
  __syncthreads();

  if (lane < 16) {
    const int orow = rowbase + lane;
    float wv[21];
#pragma unroll
    for (int c = 0; c < 21; ++c) wv[c] = redw[lane * 33 + c];
    const float x = xp[orow], z = zp[orow], t = tp[orow];
    const float x2 = fmaf(x, x, -1.f), z2 = fmaf(z, z, -1.f);
    float* o = out;
    atomicAdd(&o[0 * NPTS + orow],  wv[10] - x * wv[9]);                     // dudx
    atomicAdd(&o[1 * NPTS + orow],  wv[11] - z * wv[9]);                     // dudz
    atomicAdd(&o[2 * NPTS + orow],  wv[12] - t * wv[9]);                     // dudt
    atomicAdd(&o[3 * NPTS + orow],  wv[16] - x * wv[15]);                    // dwdx
    atomicAdd(&o[4 * NPTS + orow],  wv[17] - z * wv[15]);                    // dwdz
    atomicAdd(&o[5 * NPTS + orow],  wv[18] - t * wv[15]);                    // dwdt
    atomicAdd(&o[6 * NPTS + orow],  wv[4]  - x * wv[3]);                     // dbdx
    atomicAdd(&o[7 * NPTS + orow],  wv[5]  - z * wv[3]);                     // dbdz
    atomicAdd(&o[8 * NPTS + orow],  wv[6]  - t * wv[3]);                     // dbdt
    atomicAdd(&o[9 * NPTS + orow],  wv[1]  - x * wv[0]);                     // dpdx
    atomicAdd(&o[10 * NPTS + orow], wv[2]  - z * wv[0]);                     // dpdz
    atomicAdd(&o[11 * NPTS + orow], wv[13] - 2.f * x * wv[10] + x2 * wv[9]); // d2u2x
    atomicAdd(&o[12 * NPTS + orow], wv[14] - 2.f * z * wv[11] + z2 * wv[9]); // d2u2z
    atomicAdd(&o[13 * NPTS + orow], wv[19] - 2.f * x * wv[16] + x2 * wv[15]);// d2w2x
    atomicAdd(&o[14 * NPTS + orow], wv[20] - 2.f * z * wv[17] + z2 * wv[15]);// d2w2z
    atomicAdd(&o[15 * NPTS + orow], wv[7]  - 2.f * x * wv[4]  + x2 * wv[3]); // d2b2x
    atomicAdd(&o[16 * NPTS + orow], wv[8]  - 2.f * z * wv[5]  + z2 * wv[3]); // d2b2z
  }
}

extern "C" void kernel_launch(void* const* d_in, const int* in_sizes, int n_in,
                              void* d_out, int out_size, void* d_ws, size_t ws_size,
                              hipStream_t stream) {
  const float* xp  = (const float*)d_in[0];
  const float* zp  = (const float*)d_in[1];
  const float* tp  = (const float*)d_in[2];
  const float* cp  = (const float*)d_in[3];
  const float* v1p = (const float*)d_in[4];
  const float* v2p = (const float*)d_in[5];
  const float* v3p = (const float*)d_in[6];
  const float* v4p = (const float*)d_in[7];

  float* ws  = (float*)d_ws;
  float* cxa = ws;
  float* cza = ws + NPTS;
  float* cta = ws + 2 * NPTS;
  __bf16* vt = (__bf16*)(ws + 3 * NPTS);

  rbf_prep<<<NPTS / 256, 256, 0, stream>>>(cp, v1p, v2p, v3p, v4p,
                                           cxa, cza, cta, vt, (float*)d_out);

  rbf_main3<<<96 * SPLIT, 256, 0, stream>>>(xp, zp, tp, cxa, cza, cta, vt,
                                            (float*)d_out);
}